// Round 1
// baseline (801.315 us; speedup 1.0000x reference)
//
#include <hip/hip_runtime.h>
#include <hip/hip_bf16.h>
#include <stdint.h>

// Problem constants
#define NB 4
#define SS 4096
#define DD 256

typedef __attribute__((ext_vector_type(8))) short bf16x8;
typedef __attribute__((ext_vector_type(4))) float f32x4;

__device__ __forceinline__ float bf2f(uint16_t u) {
    union { uint32_t i; float f; } v; v.i = ((uint32_t)u) << 16; return v.f;
}
__device__ __forceinline__ uint16_t f2bf(float f) {
    union { float ff; uint32_t i; } v; v.ff = f;
    uint32_t r = v.i + 0x7FFFu + ((v.i >> 16) & 1u);
    return (uint16_t)(r >> 16);
}

__device__ __forceinline__ void gload_lds16(const uint16_t* g, uint16_t* l) {
    __builtin_amdgcn_global_load_lds((const __attribute__((address_space(1))) void*)g,
                                     (__attribute__((address_space(3))) void*)l, 16, 0, 0);
}

// fp32 -> bf16 cast, 8 elems/thread
__global__ __launch_bounds__(256) void cast_f32_bf16(const float* __restrict__ in,
                                                     uint16_t* __restrict__ out, long n) {
    long i = ((long)blockIdx.x * 256 + threadIdx.x) * 8;
    if (i + 8 > n) return;
    float4 a = *(const float4*)(in + i);
    float4 b = *(const float4*)(in + i + 4);
    uint32_t w0 = (uint32_t)f2bf(a.x) | ((uint32_t)f2bf(a.y) << 16);
    uint32_t w1 = (uint32_t)f2bf(a.z) | ((uint32_t)f2bf(a.w) << 16);
    uint32_t w2 = (uint32_t)f2bf(b.x) | ((uint32_t)f2bf(b.y) << 16);
    uint32_t w3 = (uint32_t)f2bf(b.z) | ((uint32_t)f2bf(b.w) << 16);
    uint4 o; o.x = w0; o.y = w1; o.z = w2; o.w = w3;
    *(uint4*)(out + i) = o;
}

// [256,256] f32 row-major [k][n] -> bf16 [n][k]  (B^T layout for GEMMs)
__global__ __launch_bounds__(256) void transpose_cast_w(const float* __restrict__ in,
                                                        uint16_t* __restrict__ out) {
    int t = blockIdx.x * 256 + threadIdx.x;  // 0..65535
    int n = t >> 8, k = t & 255;
    out[t] = f2bf(in[k * 256 + n]);
}

// generic bf16 [R,C] -> [C,R] tile transpose, batched
__global__ __launch_bounds__(256) void transpose_bf16(const uint16_t* __restrict__ in,
                                                      uint16_t* __restrict__ out,
                                                      int R, int C, long ibs, long obs) {
    __shared__ uint16_t T[64][65];
    int b = blockIdx.z;
    int c0 = blockIdx.x * 64, r0 = blockIdx.y * 64;
    int t = threadIdx.x; int x = t & 63, y4 = t >> 6;
    const uint16_t* ib = in + (long)b * ibs;
    uint16_t* ob = out + (long)b * obs;
#pragma unroll
    for (int i = 0; i < 16; i++) {
        int rl = y4 + i * 4;
        T[rl][x] = ib[(long)(r0 + rl) * C + c0 + x];
    }
    __syncthreads();
#pragma unroll
    for (int i = 0; i < 16; i++) {
        int cc = y4 + i * 4;
        ob[(long)(c0 + cc) * R + r0 + x] = T[x][cc];
    }
}

// attn = (exp(dot/1024)/rowsum) * mask ; write fp32 attn (d_out) + bf16 attn^T (ws)
__global__ __launch_bounds__(256) void attn_softmax_tr(const uint16_t* __restrict__ dots,
                                                       const float* __restrict__ mask,
                                                       const float* __restrict__ rowsum,
                                                       float* __restrict__ attn_out,
                                                       uint16_t* __restrict__ attnT) {
    __shared__ float T[64][65];
    int b = blockIdx.z;
    int q0 = blockIdx.x * 64, k0 = blockIdx.y * 64;
    int t = threadIdx.x; int x = t & 63, y4 = t >> 6;
    long base = (long)b * SS * SS;
#pragma unroll
    for (int i = 0; i < 16; i++) {
        int kl = y4 + i * 4;
        int kk = k0 + kl;
        long idx = base + (long)kk * SS + q0 + x;
        float d = bf2f(dots[idx]);
        float e = __expf(d * (1.0f / 1024.0f));
        float a = e * (1.0f / rowsum[b * SS + kk]) * mask[idx];
        attn_out[idx] = a;
        T[kl][x] = a;
    }
    __syncthreads();
#pragma unroll
    for (int i = 0; i < 16; i++) {
        int qq = y4 + i * 4;
        attnT[base + (long)(q0 + qq) * SS + k0 + x] = f2bf(T[x][qq]);
    }
}

// m97-style bf16 GEMM: C[M,N] = A[M,K] * Bt[N,K]^T, 128x128 tile, BK=32, batched via z.
// EPI 0: logits  -> bf16 dots + atomic rowsum of exp(acc/1024)
// EPI 1: sign    -> bf16 sign(acc + bias[n])
// EPI 2: bf16    -> bf16 (acc + bias[n])           (vp)
// EPI 3: pv      -> bf16 tanh(acc * anchor[m,n])   (A2)
// EPI 4: dense   -> fp32 (acc + bias[n])           (final out)
template <int EPI>
__global__ __launch_bounds__(256) void gemm_bt(const uint16_t* __restrict__ A,
                                               const uint16_t* __restrict__ Bt,
                                               int M, int N, int K,
                                               long Abs, long Bbs, long Cbs,
                                               const float* __restrict__ bias,
                                               const float* __restrict__ anchor,
                                               float* __restrict__ rowsum,
                                               uint16_t* __restrict__ Cb,
                                               float* __restrict__ Cf) {
    __shared__ __align__(16) uint16_t As[128 * 32];
    __shared__ __align__(16) uint16_t Bs[128 * 32];
    const int t = threadIdx.x;
    const int l = t & 63;
    const int wid = t >> 6;
    const int wm = wid & 1, wn = wid >> 1;
    const int bz = blockIdx.z;
    const int m0 = blockIdx.y * 128;
    const int n0 = blockIdx.x * 128;

    const uint16_t* Ab = A + (long)bz * Abs + (long)m0 * K;
    const uint16_t* Bb = Bt + (long)bz * Bbs + (long)n0 * K;
    const uint16_t* ga = Ab + (long)(t >> 2) * K + (t & 3) * 8;
    const uint16_t* gb = Bb + (long)(t >> 2) * K + (t & 3) * 8;
    const long halfS = (long)64 * K;
    uint16_t* lA0 = As + (wid * 64) * 8;
    uint16_t* lA1 = As + (wid * 64) * 8 + 2048;
    uint16_t* lB0 = Bs + (wid * 64) * 8;
    uint16_t* lB1 = Bs + (wid * 64) * 8 + 2048;

    f32x4 acc[4][4];
#pragma unroll
    for (int i = 0; i < 4; i++)
#pragma unroll
        for (int j = 0; j < 4; j++) acc[i][j] = (f32x4){0.f, 0.f, 0.f, 0.f};

    const int aoff = (wm * 64 + (l & 15)) * 32 + (l >> 4) * 8;
    const int boff = (wn * 64 + (l & 15)) * 32 + (l >> 4) * 8;

    for (int kt = 0; kt < K; kt += 32) {
        if (kt) __syncthreads();
        gload_lds16(ga + kt, lA0);
        gload_lds16(ga + halfS + kt, lA1);
        gload_lds16(gb + kt, lB0);
        gload_lds16(gb + halfS + kt, lB1);
        __syncthreads();
        bf16x8 af[4], bfv[4];
#pragma unroll
        for (int i = 0; i < 4; i++) af[i] = *(const bf16x8*)(As + aoff + i * 512);
#pragma unroll
        for (int i = 0; i < 4; i++) bfv[i] = *(const bf16x8*)(Bs + boff + i * 512);
#pragma unroll
        for (int i = 0; i < 4; i++)
#pragma unroll
            for (int j = 0; j < 4; j++)
                acc[i][j] = __builtin_amdgcn_mfma_f32_16x16x32_bf16(af[i], bfv[j], acc[i][j], 0, 0, 0);
    }

    const int mb = m0 + wm * 64;
    const int nb = n0 + wn * 64;
    const int rl = (l >> 4) * 4;
    const int cl = l & 15;
    const long cbase = (long)bz * Cbs;

#pragma unroll
    for (int i = 0; i < 4; i++) {
#pragma unroll
        for (int r = 0; r < 4; r++) {
            const int mg = mb + i * 16 + rl + r;
            if constexpr (EPI == 0) {
                float s = 0.f;
#pragma unroll
                for (int j = 0; j < 4; j++) {
                    const int ng = nb + j * 16 + cl;
                    float vv = acc[i][j][r];
                    Cb[cbase + (long)mg * N + ng] = f2bf(vv);
                    s += __expf(vv * (1.0f / 1024.0f));
                }
                s += __shfl_xor(s, 1); s += __shfl_xor(s, 2);
                s += __shfl_xor(s, 4); s += __shfl_xor(s, 8);
                if (cl == 0) atomicAdd(&rowsum[(long)bz * M + mg], s);
            } else {
#pragma unroll
                for (int j = 0; j < 4; j++) {
                    const int ng = nb + j * 16 + cl;
                    float vv = acc[i][j][r];
                    if constexpr (EPI == 1) {
                        vv += bias[ng];
                        Cb[cbase + (long)mg * N + ng] =
                            (vv > 0.f) ? (uint16_t)0x3F80 : ((vv < 0.f) ? (uint16_t)0xBF80 : (uint16_t)0);
                    } else if constexpr (EPI == 2) {
                        Cb[cbase + (long)mg * N + ng] = f2bf(vv + bias[ng]);
                    } else if constexpr (EPI == 3) {
                        Cb[cbase + (long)mg * N + ng] = f2bf(tanhf(vv * anchor[(long)mg * N + ng]));
                    } else {
                        Cf[cbase + (long)mg * N + ng] = vv + bias[ng];
                    }
                }
            }
        }
    }
}

extern "C" void kernel_launch(void* const* d_in, const int* in_sizes, int n_in,
                              void* d_out, int out_size, void* d_ws, size_t ws_size,
                              hipStream_t stream) {
    const float* v_in   = (const float*)d_in[0];
    const float* k_in   = (const float*)d_in[1];
    const float* q_in   = (const float*)d_in[2];
    const float* mask   = (const float*)d_in[3];
    const float* wq_k   = (const float*)d_in[4];
    const float* wq_b   = (const float*)d_in[5];
    const float* wk_k   = (const float*)d_in[6];
    const float* wk_b   = (const float*)d_in[7];
    const float* wv_k   = (const float*)d_in[8];
    const float* wv_b   = (const float*)d_in[9];
    const float* anchor = (const float*)d_in[10];
    const float* dns_k  = (const float*)d_in[11];
    const float* dns_b  = (const float*)d_in[12];

    const long BSD = (long)NB * SS * DD;  // 4,194,304
    const long BSS = (long)NB * SS * SS;  // 67,108,864
    float* out0 = (float*)d_out;          // [B,S,D] fp32
    float* attn_out = out0 + BSD;         // [B,S,S] fp32

    // ws layout (needs ~337 MB)
    char* w = (char*)d_ws;
    auto take = [&](long bytes) -> char* { char* p = w; w += (bytes + 255) & ~255L; return p; };
    uint16_t* qb   = (uint16_t*)take(BSD * 2);
    uint16_t* kb   = (uint16_t*)take(BSD * 2);
    uint16_t* vb   = (uint16_t*)take(BSD * 2);
    uint16_t* WTq  = (uint16_t*)take(65536L * 2);
    uint16_t* WTk  = (uint16_t*)take(65536L * 2);
    uint16_t* WTv  = (uint16_t*)take(65536L * 2);
    uint16_t* DT   = (uint16_t*)take(65536L * 2);
    uint16_t* sq   = (uint16_t*)take(BSD * 2);
    uint16_t* sk   = (uint16_t*)take(BSD * 2);
    uint16_t* vp   = (uint16_t*)take(BSD * 2);
    uint16_t* vpT  = (uint16_t*)take(BSD * 2);
    uint16_t* A2   = (uint16_t*)take(BSD * 2);
    uint16_t* dots = (uint16_t*)take(BSS * 2);
    uint16_t* attnT= (uint16_t*)take(BSS * 2);
    float* rowsum  = (float*)take((long)NB * SS * 4);

    // 1) casts + weight transposes
    cast_f32_bf16<<<dim3(BSD / 2048), 256, 0, stream>>>(q_in, qb, BSD);
    cast_f32_bf16<<<dim3(BSD / 2048), 256, 0, stream>>>(k_in, kb, BSD);
    cast_f32_bf16<<<dim3(BSD / 2048), 256, 0, stream>>>(v_in, vb, BSD);
    transpose_cast_w<<<256, 256, 0, stream>>>(wq_k, WTq);
    transpose_cast_w<<<256, 256, 0, stream>>>(wk_k, WTk);
    transpose_cast_w<<<256, 256, 0, stream>>>(wv_k, WTv);
    transpose_cast_w<<<256, 256, 0, stream>>>(dns_k, DT);
    hipMemsetAsync(rowsum, 0, (size_t)NB * SS * 4, stream);

    // 2) projections -> signs (q,k) and vp
    gemm_bt<1><<<dim3(2, 128, 1), 256, 0, stream>>>(qb, WTq, 16384, 256, 256, 0, 0, 0,
                                                    wq_b, nullptr, nullptr, sq, nullptr);
    gemm_bt<1><<<dim3(2, 128, 1), 256, 0, stream>>>(kb, WTk, 16384, 256, 256, 0, 0, 0,
                                                    wk_b, nullptr, nullptr, sk, nullptr);
    gemm_bt<2><<<dim3(2, 128, 1), 256, 0, stream>>>(vb, WTv, 16384, 256, 256, 0, 0, 0,
                                                    wv_b, nullptr, nullptr, vp, nullptr);
    transpose_bf16<<<dim3(4, 64, NB), 256, 0, stream>>>(vp, vpT, SS, DD,
                                                        (long)SS * DD, (long)SS * DD);

    // 3) logits = sk . sq^T (exact in bf16) + fused exp-rowsum
    gemm_bt<0><<<dim3(32, 32, NB), 256, 0, stream>>>(sk, sq, SS, SS, DD,
                                                     (long)SS * DD, (long)SS * DD, (long)SS * SS,
                                                     nullptr, nullptr, rowsum, dots, nullptr);

    // 4) attn = softmax * mask -> fp32 out + bf16 transposed copy
    attn_softmax_tr<<<dim3(64, 64, NB), 256, 0, stream>>>(dots, mask, rowsum, attn_out, attnT);

    // 5) out = attn^T @ vp, fused tanh(.*anchor) -> bf16 A2
    gemm_bt<3><<<dim3(2, 32, NB), 256, 0, stream>>>(attnT, vpT, SS, DD, SS,
                                                    (long)SS * SS, (long)SS * DD, (long)SS * DD,
                                                    nullptr, anchor, nullptr, A2, nullptr);

    // 6) final dense + bias -> fp32 d_out
    gemm_bt<4><<<dim3(2, 128, 1), 256, 0, stream>>>(A2, DT, 16384, 256, 256, 0, 0, 0,
                                                    dns_b, nullptr, nullptr, nullptr, out0);
}

// Round 2
// 779.209 us; speedup vs baseline: 1.0284x; 1.0284x over previous
//
#include <hip/hip_runtime.h>
#include <hip/hip_bf16.h>
#include <stdint.h>

// Problem constants
#define NB 4
#define SS 4096
#define DD 256

typedef __attribute__((ext_vector_type(8))) short bf16x8;
typedef __attribute__((ext_vector_type(4))) float f32x4;

__device__ __forceinline__ float bf2f(uint16_t u) {
    union { uint32_t i; float f; } v; v.i = ((uint32_t)u) << 16; return v.f;
}
__device__ __forceinline__ uint16_t f2bf(float f) {
    union { float ff; uint32_t i; } v; v.ff = f;
    uint32_t r = v.i + 0x7FFFu + ((v.i >> 16) & 1u);
    return (uint16_t)(r >> 16);
}

__device__ __forceinline__ void gload_lds16(const uint16_t* g, uint16_t* l) {
    __builtin_amdgcn_global_load_lds((const __attribute__((address_space(1))) void*)g,
                                     (__attribute__((address_space(3))) void*)l, 16, 0, 0);
}

// fp32 -> bf16 cast, 8 elems/thread
__global__ __launch_bounds__(256) void cast_f32_bf16(const float* __restrict__ in,
                                                     uint16_t* __restrict__ out, long n) {
    long i = ((long)blockIdx.x * 256 + threadIdx.x) * 8;
    if (i + 8 > n) return;
    float4 a = *(const float4*)(in + i);
    float4 b = *(const float4*)(in + i + 4);
    uint4 o;
    o.x = (uint32_t)f2bf(a.x) | ((uint32_t)f2bf(a.y) << 16);
    o.y = (uint32_t)f2bf(a.z) | ((uint32_t)f2bf(a.w) << 16);
    o.z = (uint32_t)f2bf(b.x) | ((uint32_t)f2bf(b.y) << 16);
    o.w = (uint32_t)f2bf(b.z) | ((uint32_t)f2bf(b.w) << 16);
    *(uint4*)(out + i) = o;
}

// 4x [256,256] f32 [k][n] -> bf16 [n][k]
__global__ __launch_bounds__(256) void transpose_cast_w4(const float* __restrict__ a0, const float* __restrict__ a1,
                                                         const float* __restrict__ a2, const float* __restrict__ a3,
                                                         uint16_t* __restrict__ o0, uint16_t* __restrict__ o1,
                                                         uint16_t* __restrict__ o2, uint16_t* __restrict__ o3) {
    const float* in; uint16_t* out;
    switch (blockIdx.y) {
        case 0: in = a0; out = o0; break;
        case 1: in = a1; out = o1; break;
        case 2: in = a2; out = o2; break;
        default: in = a3; out = o3; break;
    }
    int t = blockIdx.x * 256 + threadIdx.x;
    int n = t >> 8, k = t & 255;
    out[t] = f2bf(in[k * 256 + n]);
}

// generic bf16 [R,C] -> [C,R] tile transpose, batched
__global__ __launch_bounds__(256) void transpose_bf16(const uint16_t* __restrict__ in,
                                                      uint16_t* __restrict__ out,
                                                      int R, int C, long ibs, long obs) {
    __shared__ uint16_t T[64][65];
    int b = blockIdx.z;
    int c0 = blockIdx.x * 64, r0 = blockIdx.y * 64;
    int t = threadIdx.x; int x = t & 63, y4 = t >> 6;
    const uint16_t* ib = in + (long)b * ibs;
    uint16_t* ob = out + (long)b * obs;
#pragma unroll
    for (int i = 0; i < 16; i++) {
        int rl = y4 + i * 4;
        T[rl][x] = ib[(long)(r0 + rl) * C + c0 + x];
    }
    __syncthreads();
#pragma unroll
    for (int i = 0; i < 16; i++) {
        int cc = y4 + i * 4;
        ob[(long)(c0 + cc) * R + r0 + x] = T[x][cc];
    }
}

// m97-style bf16 GEMM: C[M,N] = A[M,K] * Bt[N,K]^T, 128x128 tile, BK=32, batched via z.
// EPI 1: sign    -> bf16 sign(acc + bias[n])
// EPI 2: bf16    -> bf16 (acc + bias[n])
// EPI 4: dense   -> fp32 (acc + bias[n])
// EPI 5: rowsum only: atomicAdd rowsum[m] += sum_n exp(acc/1024)
template <int EPI>
__global__ __launch_bounds__(256) void gemm_bt(const uint16_t* __restrict__ A,
                                               const uint16_t* __restrict__ Bt,
                                               int M, int N, int K,
                                               long Abs, long Bbs, long Cbs,
                                               const float* __restrict__ bias,
                                               float* __restrict__ rowsum,
                                               uint16_t* __restrict__ Cb,
                                               float* __restrict__ Cf) {
    __shared__ __align__(16) uint16_t As[128 * 32];
    __shared__ __align__(16) uint16_t Bs[128 * 32];
    const int t = threadIdx.x;
    const int l = t & 63;
    const int wid = t >> 6;
    const int wm = wid & 1, wn = wid >> 1;
    const int bz = blockIdx.z;
    const int m0 = blockIdx.y * 128;
    const int n0 = blockIdx.x * 128;

    const uint16_t* Ab = A + (long)bz * Abs + (long)m0 * K;
    const uint16_t* Bb = Bt + (long)bz * Bbs + (long)n0 * K;
    const uint16_t* ga = Ab + (long)(t >> 2) * K + (t & 3) * 8;
    const uint16_t* gb = Bb + (long)(t >> 2) * K + (t & 3) * 8;
    const long halfS = (long)64 * K;
    uint16_t* lA0 = As + (wid * 64) * 8;
    uint16_t* lA1 = As + (wid * 64) * 8 + 2048;
    uint16_t* lB0 = Bs + (wid * 64) * 8;
    uint16_t* lB1 = Bs + (wid * 64) * 8 + 2048;

    f32x4 acc[4][4];
#pragma unroll
    for (int i = 0; i < 4; i++)
#pragma unroll
        for (int j = 0; j < 4; j++) acc[i][j] = (f32x4){0.f, 0.f, 0.f, 0.f};

    const int aoff = (wm * 64 + (l & 15)) * 32 + (l >> 4) * 8;
    const int boff = (wn * 64 + (l & 15)) * 32 + (l >> 4) * 8;

    for (int kt = 0; kt < K; kt += 32) {
        if (kt) __syncthreads();
        gload_lds16(ga + kt, lA0);
        gload_lds16(ga + halfS + kt, lA1);
        gload_lds16(gb + kt, lB0);
        gload_lds16(gb + halfS + kt, lB1);
        __syncthreads();
        bf16x8 af[4], bfv[4];
#pragma unroll
        for (int i = 0; i < 4; i++) af[i] = *(const bf16x8*)(As + aoff + i * 512);
#pragma unroll
        for (int i = 0; i < 4; i++) bfv[i] = *(const bf16x8*)(Bs + boff + i * 512);
#pragma unroll
        for (int i = 0; i < 4; i++)
#pragma unroll
            for (int j = 0; j < 4; j++)
                acc[i][j] = __builtin_amdgcn_mfma_f32_16x16x32_bf16(af[i], bfv[j], acc[i][j], 0, 0, 0);
    }

    const int mb = m0 + wm * 64;
    const int nb = n0 + wn * 64;
    const int rl = (l >> 4) * 4;
    const int cl = l & 15;
    const long cbase = (long)bz * Cbs;

#pragma unroll
    for (int i = 0; i < 4; i++) {
#pragma unroll
        for (int r = 0; r < 4; r++) {
            const int mg = mb + i * 16 + rl + r;
            if constexpr (EPI == 5) {
                float s = 0.f;
#pragma unroll
                for (int j = 0; j < 4; j++) s += __expf(acc[i][j][r] * (1.0f / 1024.0f));
                s += __shfl_xor(s, 1); s += __shfl_xor(s, 2);
                s += __shfl_xor(s, 4); s += __shfl_xor(s, 8);
                if (cl == 0) atomicAdd(&rowsum[(long)bz * M + mg], s);
            } else {
#pragma unroll
                for (int j = 0; j < 4; j++) {
                    const int ng = nb + j * 16 + cl;
                    float vv = acc[i][j][r];
                    if constexpr (EPI == 1) {
                        vv += bias[ng];
                        Cb[cbase + (long)mg * N + ng] =
                            (vv > 0.f) ? (uint16_t)0x3F80 : ((vv < 0.f) ? (uint16_t)0xBF80 : (uint16_t)0);
                    } else if constexpr (EPI == 2) {
                        Cb[cbase + (long)mg * N + ng] = f2bf(vv + bias[ng]);
                    } else {
                        Cf[cbase + (long)mg * N + ng] = vv + bias[ng];
                    }
                }
            }
        }
    }
}

// ---------------- Fused attention + PV kernel ----------------
// grid (SS/64, NB), block 512 (8 waves).
// Per block: q-tile of 64, iterate k-tiles of 32 over full S.
//   logits[k,q] = sk . sq^T via MFMA (sk staged LDS dbuf, sq frags in regs)
//   attn = exp(l/1024)*rcp(rowsum[k])*mask  -> fp32 global + bf16 Ts (A-layout)
//   out[q,d] += attn^T @ vp  via MFMA (vpT frags straight from global)
// Final: A2 = bf16(tanh(out * anchor))
__global__ __launch_bounds__(512, 2) void fused_attn_pv(const uint16_t* __restrict__ sk,
                                                        const uint16_t* __restrict__ sq,
                                                        const uint16_t* __restrict__ vpT,
                                                        const float* __restrict__ mask,
                                                        const float* __restrict__ rowsum,
                                                        const float* __restrict__ anchor,
                                                        float* __restrict__ attn_out,
                                                        uint16_t* __restrict__ A2) {
    // Ks: [2 bufs][8 dc][32 k][32 d] bf16 (chunked so frag rows stride 64B)
    __shared__ __align__(16) uint16_t Ks[2 * 8192];
    // Ts: [64 q][40 k] bf16 (pad 32->40: 16B-aligned rows, 2-way-free banks)
    __shared__ __align__(16) uint16_t Ts[64 * 40];

    const int t = threadIdx.x;
    const int w = t >> 6;          // wave 0..7
    const int l = t & 63;
    const int quad = l >> 4;
    const int l15 = l & 15;
    const int kh = w & 1;          // logits k-half (16 rows)
    const int qq = w >> 2 == 0 ? (w >> 1) : (w >> 1);  // q-quarter 0..3
    const int qql = w >> 1;
    const int dsl = w * 32;        // PV d-slice base

    const int b = blockIdx.y;
    const int q0 = blockIdx.x * 64;

    const uint16_t* sqb = sq + (long)b * SS * DD;
    const uint16_t* skb = sk + (long)b * SS * DD;
    const uint16_t* vtb = vpT + (long)b * SS * DD;  // [256][4096]
    const float* maskb = mask + (long)b * SS * SS;
    float* attnb = attn_out + (long)b * SS * SS;
    const float* rsb = rowsum + (long)b * SS;

    // Q fragments in registers: wave's q-quarter [16 q][256 d] = 8 frags
    bf16x8 qf[8];
#pragma unroll
    for (int s = 0; s < 8; s++)
        qf[s] = *(const bf16x8*)(sqb + (long)(q0 + qql * 16 + l15) * DD + s * 32 + quad * 8);

    // PV accumulators: [4 qi][2 dj]
    f32x4 acc[4][2];
#pragma unroll
    for (int i = 0; i < 4; i++) { acc[i][0] = (f32x4){0,0,0,0}; acc[i][1] = (f32x4){0,0,0,0}; }

    // staging helper: wave w stages dc=w, two k-halves
    const uint16_t* gK = skb + (long)(l >> 2) * DD + w * 32 + (l & 3) * 8;

    // prologue stage buf0, kt=0
    {
        uint16_t* base = Ks + w * 1024;
        gload_lds16(gK, base);
        gload_lds16(gK + 16 * DD, base + 512);
    }

    const int NIT = SS / 32;
    for (int it = 0; it < NIT; ++it) {
        const int kt = it * 32;
        __syncthreads();  // (A) buf[it&1] staged; prev PV's Ts reads done

        if (it + 1 < NIT) {
            uint16_t* base = Ks + ((it + 1) & 1) * 8192 + w * 1024;
            const uint16_t* g = gK + (long)(kt + 32) * DD;
            gload_lds16(g, base);
            gload_lds16(g + 16 * DD, base + 512);
        }

        // prefetch V fragments (global->regs), mask, rowsum
        bf16x8 vf0 = *(const bf16x8*)(vtb + (long)(dsl + l15) * SS + kt + quad * 8);
        bf16x8 vf1 = *(const bf16x8*)(vtb + (long)(dsl + 16 + l15) * SS + kt + quad * 8);
        const int kg0 = kt + kh * 16 + quad * 4;
        float mr[4], inv[4];
#pragma unroll
        for (int r = 0; r < 4; r++) mr[r] = maskb[(long)(kg0 + r) * SS + q0 + qql * 16 + l15];
#pragma unroll
        for (int r = 0; r < 4; r++) inv[r] = __builtin_amdgcn_rcpf(rsb[kg0 + r]);

        // logits MFMA: this wave's [16k x 16q] piece, contraction over d=256
        f32x4 lacc = (f32x4){0, 0, 0, 0};
        const uint16_t* kbuf = Ks + (it & 1) * 8192;
#pragma unroll
        for (int s = 0; s < 8; s++) {
            bf16x8 kf = *(const bf16x8*)(kbuf + s * 1024 + (kh * 16 + l15) * 32 + quad * 8);
            lacc = __builtin_amdgcn_mfma_f32_16x16x32_bf16(kf, qf[s], lacc, 0, 0, 0);
        }

        // epilogue: attn value, store fp32, pack into Ts
        float av[4];
#pragma unroll
        for (int r = 0; r < 4; r++) {
            float e = __expf(lacc[r] * (1.0f / 1024.0f));
            float a = e * inv[r] * mr[r];
            attnb[(long)(kg0 + r) * SS + q0 + qql * 16 + l15] = a;
            av[r] = a;
        }
        uint2 pk;
        pk.x = (uint32_t)f2bf(av[0]) | ((uint32_t)f2bf(av[1]) << 16);
        pk.y = (uint32_t)f2bf(av[2]) | ((uint32_t)f2bf(av[3]) << 16);
        *(uint2*)&Ts[(qql * 16 + l15) * 40 + kh * 16 + quad * 4] = pk;

        __syncthreads();  // (B) Ts visible

        // PV MFMA: out[64q x 32d-slice] += Ts[q][k] * vpT[d][k]
#pragma unroll
        for (int qi = 0; qi < 4; qi++) {
            bf16x8 tf = *(const bf16x8*)(Ts + (qi * 16 + l15) * 40 + quad * 8);
            acc[qi][0] = __builtin_amdgcn_mfma_f32_16x16x32_bf16(tf, vf0, acc[qi][0], 0, 0, 0);
            acc[qi][1] = __builtin_amdgcn_mfma_f32_16x16x32_bf16(tf, vf1, acc[qi][1], 0, 0, 0);
        }
    }

    // final epilogue: A2 = bf16(tanh(acc * anchor))
    uint16_t* A2b = A2 + (long)b * SS * DD;
#pragma unroll
    for (int qi = 0; qi < 4; qi++) {
#pragma unroll
        for (int dj = 0; dj < 2; dj++) {
#pragma unroll
            for (int r = 0; r < 4; r++) {
                const int q = q0 + qi * 16 + quad * 4 + r;
                const int d = dsl + dj * 16 + l15;
                float o = acc[qi][dj][r];
                A2b[(long)q * DD + d] = f2bf(tanhf(o * anchor[(long)q * DD + d]));
            }
        }
    }
}

extern "C" void kernel_launch(void* const* d_in, const int* in_sizes, int n_in,
                              void* d_out, int out_size, void* d_ws, size_t ws_size,
                              hipStream_t stream) {
    const float* v_in   = (const float*)d_in[0];
    const float* k_in   = (const float*)d_in[1];
    const float* q_in   = (const float*)d_in[2];
    const float* mask   = (const float*)d_in[3];
    const float* wq_k   = (const float*)d_in[4];
    const float* wq_b   = (const float*)d_in[5];
    const float* wk_k   = (const float*)d_in[6];
    const float* wk_b   = (const float*)d_in[7];
    const float* wv_k   = (const float*)d_in[8];
    const float* wv_b   = (const float*)d_in[9];
    const float* anchor = (const float*)d_in[10];
    const float* dns_k  = (const float*)d_in[11];
    const float* dns_b  = (const float*)d_in[12];

    const long BSD = (long)NB * SS * DD;  // 4,194,304
    float* out0 = (float*)d_out;          // [B,S,D] fp32
    float* attn_out = out0 + BSD;         // [B,S,S] fp32

    // ws layout (~63 MB)
    char* w = (char*)d_ws;
    auto take = [&](long bytes) -> char* { char* p = w; w += (bytes + 255) & ~255L; return p; };
    uint16_t* qb   = (uint16_t*)take(BSD * 2);
    uint16_t* kb   = (uint16_t*)take(BSD * 2);
    uint16_t* vb   = (uint16_t*)take(BSD * 2);
    uint16_t* WTq  = (uint16_t*)take(65536L * 2);
    uint16_t* WTk  = (uint16_t*)take(65536L * 2);
    uint16_t* WTv  = (uint16_t*)take(65536L * 2);
    uint16_t* DT   = (uint16_t*)take(65536L * 2);
    uint16_t* sq   = (uint16_t*)take(BSD * 2);
    uint16_t* sk   = (uint16_t*)take(BSD * 2);
    uint16_t* vp   = (uint16_t*)take(BSD * 2);
    uint16_t* vpT  = (uint16_t*)take(BSD * 2);
    uint16_t* A2   = (uint16_t*)take(BSD * 2);
    float* rowsum  = (float*)take((long)NB * SS * 4);

    hipMemsetAsync(rowsum, 0, (size_t)NB * SS * 4, stream);

    // 1) casts + weight transposes
    cast_f32_bf16<<<dim3(BSD / 2048), 256, 0, stream>>>(q_in, qb, BSD);
    cast_f32_bf16<<<dim3(BSD / 2048), 256, 0, stream>>>(k_in, kb, BSD);
    cast_f32_bf16<<<dim3(BSD / 2048), 256, 0, stream>>>(v_in, vb, BSD);
    transpose_cast_w4<<<dim3(256, 4), 256, 0, stream>>>(wq_k, wk_k, wv_k, dns_k, WTq, WTk, WTv, DT);

    // 2) projections -> signs (q,k) and vp; vp -> vpT
    gemm_bt<1><<<dim3(2, 128, 1), 256, 0, stream>>>(qb, WTq, 16384, 256, 256, 0, 0, 0,
                                                    wq_b, nullptr, sq, nullptr);
    gemm_bt<1><<<dim3(2, 128, 1), 256, 0, stream>>>(kb, WTk, 16384, 256, 256, 0, 0, 0,
                                                    wk_b, nullptr, sk, nullptr);
    gemm_bt<2><<<dim3(2, 128, 1), 256, 0, stream>>>(vb, WTv, 16384, 256, 256, 0, 0, 0,
                                                    wv_b, nullptr, vp, nullptr);
    transpose_bf16<<<dim3(4, 64, NB), 256, 0, stream>>>(vp, vpT, SS, DD,
                                                        (long)SS * DD, (long)SS * DD);

    // 3) pass 1: rowsum[b,k] = sum_q exp(logits/1024)  (recompute GEMM, no store)
    gemm_bt<5><<<dim3(32, 32, NB), 256, 0, stream>>>(sk, sq, SS, SS, DD,
                                                     (long)SS * DD, (long)SS * DD, 0,
                                                     nullptr, rowsum, nullptr, nullptr);

    // 4) fused: logits -> softmax*mask -> attn fp32 + PV -> tanh(.*anchor) -> A2
    fused_attn_pv<<<dim3(SS / 64, NB), 512, 0, stream>>>(sk, sq, vpT, mask, rowsum,
                                                         anchor, attn_out, A2);

    // 5) final dense + bias -> fp32 d_out
    gemm_bt<4><<<dim3(2, 128, 1), 256, 0, stream>>>(A2, DT, 16384, 256, 256, 0, 0, 0,
                                                    dns_b, nullptr, nullptr, out0);
}